// Round 5
// baseline (227.641 us; speedup 1.0000x reference)
//
#include <hip/hip_runtime.h>

#define STEPS 10
#define EPB 512                 // elements per block (one thread per element)
#define BLOCK 512
#define SLAB_F 3072             // 512 elem * 6 floats per slab
#define CHUNK_F 256             // floats per 1024B DMA chunk (64 lanes x 16B)
#define NCHUNK 12               // chunks per slab

#define GLOAD_LDS16(gp, lp)                                            \
    __builtin_amdgcn_global_load_lds(                                  \
        (const __attribute__((address_space(1))) void*)(gp),           \
        (__attribute__((address_space(3))) void*)(lp), 16, 0, 0)

__global__ __launch_bounds__(BLOCK) void spiking_vestibular_kernel(
    const float* __restrict__ speed,
    const float* __restrict__ turn_rate,
    const float* __restrict__ predicted_turn,
    const float* __restrict__ predicted_speed,
    const float* __restrict__ noise,
    const float* __restrict__ v0,
    const float* __restrict__ u0,
    const float* __restrict__ rate0,
    float* __restrict__ out,
    int B)
{
#pragma clang fp contract(off)
    // LDS: [noiseA][noiseB][v][u][r], each SLAB_F floats (12 KB) -> 60 KB
    __shared__ float smem[5 * SLAB_F];

    const int tid = threadIdx.x;
    const int wv  = tid >> 6;            // wave 0..7
    const int ln  = tid & 63;
    const long long b0 = (long long)blockIdx.x * EPB;
    const long long nzLim = (long long)STEPS * B * 6 - CHUNK_F; // last valid chunk start
    const long long stLim = (long long)B * 6 - CHUNK_F;

    // Stage one 12KB slab: 12 chunks of 1024B, waves round-robin.
    // LDS dest is wave-uniform (HW adds lane*16); global src is per-lane.
    // Chunk-level clamp keeps lanes contiguous; clamped data is never used.
    auto stage = [&](const float* gbase, long long gstart, long long glim,
                     float* lbase) {
        for (int c = wv; c < NCHUNK; c += 8) {
            long long fs = gstart + (long long)c * CHUNK_F;
            if (fs > glim) fs = glim;
            GLOAD_LDS16(gbase + fs + ln * 4, lbase + c * CHUNK_F);
        }
    };

    // ---- prologue: stage noise[0], noise[1], v0, u0, rate0 ----
    stage(noise, ((long long)0 * B + b0) * 6, nzLim, smem);
    stage(noise, ((long long)1 * B + b0) * 6, nzLim, smem + SLAB_F);
    stage(v0,    b0 * 6, stLim, smem + 2 * SLAB_F);
    stage(u0,    b0 * 6, stLim, smem + 3 * SLAB_F);
    stage(rate0, b0 * 6, stLim, smem + 4 * SLAB_F);
    __syncthreads();   // drains all DMAs (each wave's vmcnt) + barrier

    const long long b = b0 + tid;
    const bool valid = (b < B);
    const long long bc = valid ? b : (long long)(B - 1);

    float v[6], u[6], r[6];
    {
        const float2* p = reinterpret_cast<const float2*>(&smem[2 * SLAB_F + tid * 6]);
        float2 a0 = p[0], a1 = p[1], a2 = p[2];
        v[0]=a0.x; v[1]=a0.y; v[2]=a1.x; v[3]=a1.y; v[4]=a2.x; v[5]=a2.y;
    }
    {
        const float2* p = reinterpret_cast<const float2*>(&smem[3 * SLAB_F + tid * 6]);
        float2 a0 = p[0], a1 = p[1], a2 = p[2];
        u[0]=a0.x; u[1]=a0.y; u[2]=a1.x; u[3]=a1.y; u[4]=a2.x; u[5]=a2.y;
    }
    {
        const float2* p = reinterpret_cast<const float2*>(&smem[4 * SLAB_F + tid * 6]);
        float2 a0 = p[0], a1 = p[1], a2 = p[2];
        r[0]=a0.x; r[1]=a0.y; r[2]=a1.x; r[3]=a1.y; r[4]=a2.x; r[5]=a2.y;
    }

    float tr = turn_rate[bc];
    float sp = speed[bc];
    float pt = predicted_turn[bc];
    float ps = predicted_speed[bc];

    float tilt = fminf(1.0f, (fabsf(tr) * sp) * 0.5f);

    float I[6];
    I[0] = fmaxf(0.0f, tr) * 10.0f;
    I[1] = fmaxf(0.0f, -tr) * 10.0f;
    I[2] = sp * 5.0f;
    I[3] = fmaxf(0.0f, -sp + 0.5f) * 5.0f;
    I[4] = tilt * 8.0f;
    I[5] = tilt * 8.0f;

    // ---- t-pipelined double buffer: compute t from buf[t&1]; after the
    // barrier (which also proves all waves finished reading), re-stage t+2
    // into that same buffer. The NEXT syncthreads' vmcnt-drain guarantees
    // completion before compute t+2 reads it.
#pragma unroll
    for (int t = 0; t < STEPS; ++t) {
        const float* nb = smem + (t & 1) * SLAB_F;
        float2 n0, n1, n2;
        {
            const float2* p = reinterpret_cast<const float2*>(&nb[tid * 6]);
            n0 = p[0]; n1 = p[1]; n2 = p[2];
        }
        float nz[6] = { n0.x, n0.y, n1.x, n1.y, n2.x, n2.y };
#pragma unroll
        for (int n = 0; n < 6; ++n) {
            float i_tot = I[n] + nz[n] * 0.3f + (-1.0f);
            float vv = v[n];
            float un = u[n];
            vv = vv + (((((0.04f * vv) * vv) + (5.0f * vv)) + 140.0f) - un + i_tot);
            un = un + 0.02f * ((0.2f * vv) - un);
            bool fired = (vv >= 30.0f);
            float spk = fired ? 1.0f : 0.0f;
            vv = fired ? -65.0f : vv;
            un = un + spk * 8.0f;
            r[n] = r[n] * 0.9f + spk * 0.1f;
            v[n] = vv;
            u[n] = un;
        }
        __syncthreads();
        if (t + 2 < STEPS)
            stage(noise, ((long long)(t + 2) * B + b0) * 6, nzLim,
                  smem + (t & 1) * SLAB_F);
    }

    float rsum = ((((r[0] + r[1]) + r[2]) + r[3]) + r[4]) + r[5];
    float rate_mean = rsum / 6.0f;

    // ---- TwoCompColumn relaxation: 8 substeps from zero ----
    float cb0 = 0.0f, cb1 = 0.0f, ca0 = 0.0f, ca1 = 0.0f;
#pragma unroll
    for (int k = 0; k < 8; ++k) {
        cb0 = cb0 + 0.5f * (tr - cb0);
        cb1 = cb1 + 0.5f * (sp - cb1);
        ca0 = ca0 + 0.5f * (pt - ca0);
        ca1 = ca1 + 0.5f * (ps - ca1);
    }
    float pe0 = cb0 - ca0;
    float pe1 = cb1 - ca1;
    float prec0 = 1.0f / (1.0f + pe0 * pe0);
    float prec1 = 1.0f / (1.0f + pe1 * pe1);
    float fe = 0.5f * (((prec0 * pe0) * pe0) + ((prec1 * pe1) * pe1));
    float pe_w = 0.7f * pe0 + 0.3f * pe1;
    float prec_mean = (prec0 + prec1) / 2.0f;
    float postural = (-prec_mean) * pe_w * 0.3f;

    if (valid) {
        float2* o = reinterpret_cast<float2*>(out + (size_t)b * 6);
        o[0] = make_float2(tilt, rate_mean);
        o[1] = make_float2(postural, pe_w);
        o[2] = make_float2(prec_mean, fe);
    }
}

extern "C" void kernel_launch(void* const* d_in, const int* in_sizes, int n_in,
                              void* d_out, int out_size, void* d_ws, size_t ws_size,
                              hipStream_t stream) {
    // setup_inputs order:
    // 0 heading (unused), 1 speed, 2 turn_rate, 3 predicted_turn,
    // 4 predicted_speed, 5 noise [STEPS,B,N], 6 v0, 7 u0, 8 rate0
    const float* speed           = (const float*)d_in[1];
    const float* turn_rate       = (const float*)d_in[2];
    const float* predicted_turn  = (const float*)d_in[3];
    const float* predicted_speed = (const float*)d_in[4];
    const float* noise           = (const float*)d_in[5];
    const float* v0              = (const float*)d_in[6];
    const float* u0              = (const float*)d_in[7];
    const float* rate0           = (const float*)d_in[8];
    float* out                   = (float*)d_out;

    int B = in_sizes[1];
    int grid = (B + EPB - 1) / EPB;
    spiking_vestibular_kernel<<<grid, BLOCK, 0, stream>>>(
        speed, turn_rate, predicted_turn, predicted_speed,
        noise, v0, u0, rate0, out, B);
}

// Round 6
// 209.785 us; speedup vs baseline: 1.0851x; 1.0851x over previous
//
#include <hip/hip_runtime.h>

#define STEPS 10

typedef float vf2 __attribute__((ext_vector_type(2)));

__global__ __launch_bounds__(256, 4) void spiking_vestibular_kernel(
    const float* __restrict__ speed,
    const float* __restrict__ turn_rate,
    const float* __restrict__ predicted_turn,
    const float* __restrict__ predicted_speed,
    const float* __restrict__ noise,
    const float* __restrict__ v0,
    const float* __restrict__ u0,
    const float* __restrict__ rate0,
    float* __restrict__ out,
    int B)
{
#pragma clang fp contract(off)
    int b = blockIdx.x * blockDim.x + threadIdx.x;
    if (b >= B) return;

    size_t base6 = (size_t)b * 6;

    // ---- issue ALL reads up front, nontemporal (bypass L1 allocate) ----
    vf2 nzv[STEPS][3];
#pragma unroll
    for (int t = 0; t < STEPS; ++t) {
        const vf2* p = reinterpret_cast<const vf2*>(noise + (size_t)t * (size_t)B * 6 + base6);
        nzv[t][0] = __builtin_nontemporal_load(p);
        nzv[t][1] = __builtin_nontemporal_load(p + 1);
        nzv[t][2] = __builtin_nontemporal_load(p + 2);
    }
    vf2 v2[3], u2[3], r2[3];
    {
        const vf2* p = reinterpret_cast<const vf2*>(v0 + base6);
        v2[0] = __builtin_nontemporal_load(p);
        v2[1] = __builtin_nontemporal_load(p + 1);
        v2[2] = __builtin_nontemporal_load(p + 2);
    }
    {
        const vf2* p = reinterpret_cast<const vf2*>(u0 + base6);
        u2[0] = __builtin_nontemporal_load(p);
        u2[1] = __builtin_nontemporal_load(p + 1);
        u2[2] = __builtin_nontemporal_load(p + 2);
    }
    {
        const vf2* p = reinterpret_cast<const vf2*>(rate0 + base6);
        r2[0] = __builtin_nontemporal_load(p);
        r2[1] = __builtin_nontemporal_load(p + 1);
        r2[2] = __builtin_nontemporal_load(p + 2);
    }
    float tr = __builtin_nontemporal_load(turn_rate + b);
    float sp = __builtin_nontemporal_load(speed + b);
    float pt = __builtin_nontemporal_load(predicted_turn + b);
    float ps = __builtin_nontemporal_load(predicted_speed + b);

    // keep every load above, all in flight, before any compute is scheduled
    __builtin_amdgcn_sched_barrier(0);

    float v[6] = { v2[0].x, v2[0].y, v2[1].x, v2[1].y, v2[2].x, v2[2].y };
    float u[6] = { u2[0].x, u2[0].y, u2[1].x, u2[1].y, u2[2].x, u2[2].y };
    float r[6] = { r2[0].x, r2[0].y, r2[1].x, r2[1].y, r2[2].x, r2[2].y };

    float tilt = fminf(1.0f, (fabsf(tr) * sp) * 0.5f);

    float I[6];
    I[0] = fmaxf(0.0f, tr) * 10.0f;
    I[1] = fmaxf(0.0f, -tr) * 10.0f;
    I[2] = sp * 5.0f;
    I[3] = fmaxf(0.0f, -sp + 0.5f) * 5.0f;
    I[4] = tilt * 8.0f;
    I[5] = tilt * 8.0f;

    // ---- Izhikevich recurrence, fully unrolled, reference fp order ----
#pragma unroll
    for (int t = 0; t < STEPS; ++t) {
        float nz[6] = { nzv[t][0].x, nzv[t][0].y,
                        nzv[t][1].x, nzv[t][1].y,
                        nzv[t][2].x, nzv[t][2].y };
#pragma unroll
        for (int n = 0; n < 6; ++n) {
            float i_tot = I[n] + nz[n] * 0.3f + (-1.0f);
            float vv = v[n];
            float un = u[n];
            vv = vv + (((((0.04f * vv) * vv) + (5.0f * vv)) + 140.0f) - un + i_tot);
            un = un + 0.02f * ((0.2f * vv) - un);
            bool fired = (vv >= 30.0f);
            float spk = fired ? 1.0f : 0.0f;
            vv = fired ? -65.0f : vv;
            un = un + spk * 8.0f;
            r[n] = r[n] * 0.9f + spk * 0.1f;
            v[n] = vv;
            u[n] = un;
        }
    }

    float rsum = ((((r[0] + r[1]) + r[2]) + r[3]) + r[4]) + r[5];
    float rate_mean = rsum / 6.0f;

    // ---- TwoCompColumn relaxation: 8 substeps from zero ----
    float cb0 = 0.0f, cb1 = 0.0f, ca0 = 0.0f, ca1 = 0.0f;
#pragma unroll
    for (int k = 0; k < 8; ++k) {
        cb0 = cb0 + 0.5f * (tr - cb0);
        cb1 = cb1 + 0.5f * (sp - cb1);
        ca0 = ca0 + 0.5f * (pt - ca0);
        ca1 = ca1 + 0.5f * (ps - ca1);
    }
    float pe0 = cb0 - ca0;
    float pe1 = cb1 - ca1;
    float prec0 = 1.0f / (1.0f + pe0 * pe0);
    float prec1 = 1.0f / (1.0f + pe1 * pe1);
    float fe = 0.5f * (((prec0 * pe0) * pe0) + ((prec1 * pe1) * pe1));
    float pe_w = 0.7f * pe0 + 0.3f * pe1;
    float prec_mean = (prec0 + prec1) / 2.0f;
    float postural = (-prec_mean) * pe_w * 0.3f;

    vf2* o = reinterpret_cast<vf2*>(out + base6);
    vf2 o0; o0.x = tilt;      o0.y = rate_mean;
    vf2 o1; o1.x = postural;  o1.y = pe_w;
    vf2 o2; o2.x = prec_mean; o2.y = fe;
    __builtin_nontemporal_store(o0, o);
    __builtin_nontemporal_store(o1, o + 1);
    __builtin_nontemporal_store(o2, o + 2);
}

extern "C" void kernel_launch(void* const* d_in, const int* in_sizes, int n_in,
                              void* d_out, int out_size, void* d_ws, size_t ws_size,
                              hipStream_t stream) {
    // setup_inputs order:
    // 0 heading (unused), 1 speed, 2 turn_rate, 3 predicted_turn,
    // 4 predicted_speed, 5 noise [STEPS,B,N], 6 v0, 7 u0, 8 rate0
    const float* speed           = (const float*)d_in[1];
    const float* turn_rate       = (const float*)d_in[2];
    const float* predicted_turn  = (const float*)d_in[3];
    const float* predicted_speed = (const float*)d_in[4];
    const float* noise           = (const float*)d_in[5];
    const float* v0              = (const float*)d_in[6];
    const float* u0              = (const float*)d_in[7];
    const float* rate0           = (const float*)d_in[8];
    float* out                   = (float*)d_out;

    int B = in_sizes[1];
    int block = 256;
    int grid = (B + block - 1) / block;
    spiking_vestibular_kernel<<<grid, block, 0, stream>>>(
        speed, turn_rate, predicted_turn, predicted_speed,
        noise, v0, u0, rate0, out, B);
}

// Round 7
// 207.734 us; speedup vs baseline: 1.0958x; 1.0099x over previous
//
#include <hip/hip_runtime.h>

#define STEPS 10

typedef float vf2 __attribute__((ext_vector_type(2)));

// 4 lanes per batch element: lane g in {0,1,2} owns neurons {2g, 2g+1};
// lane g==3 is a passenger (duplicate loads, no store) so shuffles stay defined.
__global__ __launch_bounds__(256, 6) void spiking_vestibular_kernel(
    const float* __restrict__ speed,
    const float* __restrict__ turn_rate,
    const float* __restrict__ predicted_turn,
    const float* __restrict__ predicted_speed,
    const float* __restrict__ noise,
    const float* __restrict__ v0,
    const float* __restrict__ u0,
    const float* __restrict__ rate0,
    float* __restrict__ out,
    int B)
{
#pragma clang fp contract(off)
    int tid = blockIdx.x * blockDim.x + threadIdx.x;
    int b = tid >> 2;
    int g = tid & 3;
    if (b >= B) return;

    size_t base6 = (size_t)b * 6;
    int goff = (g == 3) ? 0 : (2 * g);   // lane 3 duplicates lane 0 (in-bounds)

    // ---- issue ALL reads up front, nontemporal (bypass L1 allocation) ----
    vf2 nz[STEPS];
#pragma unroll
    for (int t = 0; t < STEPS; ++t)
        nz[t] = __builtin_nontemporal_load(
            reinterpret_cast<const vf2*>(noise + (size_t)t * (size_t)B * 6 + base6 + goff));

    vf2 v2 = __builtin_nontemporal_load(reinterpret_cast<const vf2*>(v0    + base6 + goff));
    vf2 u2 = __builtin_nontemporal_load(reinterpret_cast<const vf2*>(u0    + base6 + goff));
    vf2 r2 = __builtin_nontemporal_load(reinterpret_cast<const vf2*>(rate0 + base6 + goff));

    float tr = __builtin_nontemporal_load(turn_rate + b);
    float sp = __builtin_nontemporal_load(speed + b);
    float pt = __builtin_nontemporal_load(predicted_turn + b);
    float ps = __builtin_nontemporal_load(predicted_speed + b);

    // keep every load above in flight before any compute is scheduled
    __builtin_amdgcn_sched_barrier(0);

    float tilt = fminf(1.0f, (fabsf(tr) * sp) * 0.5f);

    float t8 = tilt * 8.0f;
    float Ia = (g == 0) ? fmaxf(0.0f, tr) * 10.0f
             : (g == 1) ? sp * 5.0f
             : t8;
    float Ib = (g == 0) ? fmaxf(0.0f, -tr) * 10.0f
             : (g == 1) ? fmaxf(0.0f, -sp + 0.5f) * 5.0f
             : t8;

    float va = v2.x, vb = v2.y;
    float ua = u2.x, ub = u2.y;
    float ra = r2.x, rb = r2.y;

#pragma unroll
    for (int t = 0; t < STEPS; ++t) {
        {   // neuron A = 2g
            float i_tot = Ia + nz[t].x * 0.3f + (-1.0f);
            float vv = va, un = ua;
            vv = vv + (((((0.04f * vv) * vv) + (5.0f * vv)) + 140.0f) - un + i_tot);
            un = un + 0.02f * ((0.2f * vv) - un);
            bool fired = (vv >= 30.0f);
            float spk = fired ? 1.0f : 0.0f;
            vv = fired ? -65.0f : vv;
            un = un + spk * 8.0f;
            ra = ra * 0.9f + spk * 0.1f;
            va = vv; ua = un;
        }
        {   // neuron B = 2g+1
            float i_tot = Ib + nz[t].y * 0.3f + (-1.0f);
            float vv = vb, un = ub;
            vv = vv + (((((0.04f * vv) * vv) + (5.0f * vv)) + 140.0f) - un + i_tot);
            un = un + 0.02f * ((0.2f * vv) - un);
            bool fired = (vv >= 30.0f);
            float spk = fired ? 1.0f : 0.0f;
            vv = fired ? -65.0f : vv;
            un = un + spk * 8.0f;
            rb = rb * 0.9f + spk * 0.1f;
            vb = vv; ub = un;
        }
    }

    // rate_mean: sum over the group's 3 active lanes (used by lane 0 only)
    float s  = ra + rb;
    float s1 = __shfl_down(s, 1, 4);
    float s2 = __shfl_down(s, 2, 4);
    float rate_mean = ((s + s1) + s2) / 6.0f;

    // ---- TwoCompColumn relaxation (redundant per lane, cheap) ----
    float cb0 = 0.0f, cb1 = 0.0f, ca0 = 0.0f, ca1 = 0.0f;
#pragma unroll
    for (int k = 0; k < 8; ++k) {
        cb0 = cb0 + 0.5f * (tr - cb0);
        cb1 = cb1 + 0.5f * (sp - cb1);
        ca0 = ca0 + 0.5f * (pt - ca0);
        ca1 = ca1 + 0.5f * (ps - ca1);
    }
    float pe0 = cb0 - ca0;
    float pe1 = cb1 - ca1;
    float prec0 = 1.0f / (1.0f + pe0 * pe0);
    float prec1 = 1.0f / (1.0f + pe1 * pe1);
    float fe = 0.5f * (((prec0 * pe0) * pe0) + ((prec1 * pe1) * pe1));
    float pe_w = 0.7f * pe0 + 0.3f * pe1;
    float prec_mean = (prec0 + prec1) / 2.0f;
    float postural = (-prec_mean) * pe_w * 0.3f;

    if (g < 3) {
        vf2 o;
        if (g == 0)      { o.x = tilt;      o.y = rate_mean; }
        else if (g == 1) { o.x = postural;  o.y = pe_w;      }
        else             { o.x = prec_mean; o.y = fe;        }
        __builtin_nontemporal_store(o, reinterpret_cast<vf2*>(out + base6 + 2 * g));
    }
}

extern "C" void kernel_launch(void* const* d_in, const int* in_sizes, int n_in,
                              void* d_out, int out_size, void* d_ws, size_t ws_size,
                              hipStream_t stream) {
    // setup_inputs order:
    // 0 heading (unused), 1 speed, 2 turn_rate, 3 predicted_turn,
    // 4 predicted_speed, 5 noise [STEPS,B,N], 6 v0, 7 u0, 8 rate0
    const float* speed           = (const float*)d_in[1];
    const float* turn_rate       = (const float*)d_in[2];
    const float* predicted_turn  = (const float*)d_in[3];
    const float* predicted_speed = (const float*)d_in[4];
    const float* noise           = (const float*)d_in[5];
    const float* v0              = (const float*)d_in[6];
    const float* u0              = (const float*)d_in[7];
    const float* rate0           = (const float*)d_in[8];
    float* out                   = (float*)d_out;

    int B = in_sizes[1];
    long long total = (long long)B * 4;
    int block = 256;
    int grid = (int)((total + block - 1) / block);
    spiking_vestibular_kernel<<<grid, block, 0, stream>>>(
        speed, turn_rate, predicted_turn, predicted_speed,
        noise, v0, u0, rate0, out, B);
}